// Round 1
// baseline (155.949 us; speedup 1.0000x reference)
//
#include <hip/hip_runtime.h>
#include <hip/hip_bf16.h>

constexpr int BATCH = 4;
constexpr int SEQ   = 1024;
constexpr int DM    = 512;     // model dim = HEADS*HDIM
constexpr int NH    = 8;
constexpr int HD    = 64;
constexpr int NQKV  = 1536;    // q(512) + k(512) + v(512) fused projection width

typedef unsigned short u16;
typedef __attribute__((ext_vector_type(8))) __bf16 bf8;
typedef __attribute__((ext_vector_type(4))) float  f4;

#define MFMA16(a, b, c) __builtin_amdgcn_mfma_f32_16x16x32_bf16(a, b, c, 0, 0, 0)

// 0.125 (1/sqrt(64)) * log2(e): q pre-scale so softmax uses exp2 directly
#define QSC 0.18033688f

static __device__ __forceinline__ u16 f2b(float f) {
    union { float f; unsigned u; } v; v.f = f;
    unsigned r = v.u + 0x7FFFu + ((v.u >> 16) & 1u);   // RNE; inputs never NaN
    return (u16)(r >> 16);
}
static __device__ __forceinline__ float fexp2(float x) {
    return __builtin_amdgcn_exp2f(x);
}
// async global->LDS, 16 B per lane (dst = wave-uniform base + lane*16)
static __device__ __forceinline__ void gl_lds16(const void* g, void* l) {
    __builtin_amdgcn_global_load_lds(
        (const __attribute__((address_space(1))) void*)g,
        (__attribute__((address_space(3))) void*)l, 16, 0, 0);
}

// ---------------------------------------------------------------------------
// Fused prep: one launch does all fp32->bf16 converts + weight transposes.
// ---------------------------------------------------------------------------
__device__ __forceinline__ void tcvt_tile(const float* __restrict__ in,
                                          u16* __restrict__ out,
                                          int R, int C, int bx, int by, int tid,
                                          float (*t)[33]) {
    int r0 = by * 32, c0 = bx * 32;
    int lc = tid & 31, lr = tid >> 5;   // lr in [0,8)
    #pragma unroll
    for (int p = 0; p < 4; p++) {
        int r = lr + p * 8;
        t[r][lc] = in[(size_t)(r0 + r) * C + c0 + lc];
    }
    __syncthreads();
    #pragma unroll
    for (int p = 0; p < 4; p++) {
        int r = lr + p * 8;
        out[(size_t)(c0 + r) * R + r0 + lc] = f2b(t[lc][r]);
    }
}

__global__ __launch_bounds__(256)
void prep(const float* __restrict__ x, const float* __restrict__ Wq,
          const float* __restrict__ Wkv, const float* __restrict__ Wout,
          const float* __restrict__ pemb,
          u16* __restrict__ xb, u16* __restrict__ qkvw,
          u16* __restrict__ Woutt, u16* __restrict__ pembb) {
    __shared__ float t[32][33];
    const int blk = blockIdx.x, tid = threadIdx.x;
    if (blk < 2048) {
        int i = (blk * 256 + tid) * 4;
        float4 v = *(const float4*)(x + i);
        ushort4 o = {f2b(v.x), f2b(v.y), f2b(v.z), f2b(v.w)};
        *(ushort4*)(xb + i) = o;
    } else if (blk < 2113) {
        int i = ((blk - 2048) * 256 + tid) * 4;
        if (i < 1025 * HD) {
            float4 v = *(const float4*)(pemb + i);
            ushort4 o = {f2b(v.x), f2b(v.y), f2b(v.z), f2b(v.w)};
            *(ushort4*)(pembb + i) = o;
        }
    } else if (blk < 2369) {
        int l = blk - 2113;
        tcvt_tile(Wq, qkvw, 512, 512, l & 15, l >> 4, tid, t);
    } else if (blk < 2881) {
        int l = blk - 2369;
        tcvt_tile(Wkv, qkvw + 512 * 512, 512, 1024, l & 31, l >> 5, tid, t);
    } else {
        int l = blk - 2881;
        tcvt_tile(Wout, Woutt, 512, 512, l & 15, l >> 4, tid, t);
    }
}

// ---------------------------------------------------------------------------
// MFMA GEMM: C[M,N] = A[M,K] @ Bt[N,K]^T  (bf16 in, fp32 acc)
// 64x128 tile. BK=128 split as 4x 32-wide sub-tiles (LDS rows stay 32 u16
// wide -> 8-way max aliasing on ds_read_b128). K=512 -> 4 outer iterations,
// i.e. half the barrier count of BK=64. LDS 48 KB -> 3 blocks/CU, which
// matches the grid-limited occupancy of the QKV projection (768 blocks).
// 256 threads = 4 waves.
// Mode 1 (Cf!=null): fp32 out + bias (the output projection).
// Mode 2 (qtb/ktb/vtb): QKV projection with fused packing —
//   col in [0,512)    -> qtb[bh][s][d], scaled by QSC
//   col in [512,1024) -> ktb[bh][t][d]
//   col in [1024,*)   -> vtb[bh][d][t]  (transposed, ushort4-packed stores)
// ---------------------------------------------------------------------------
__global__ __launch_bounds__(256)
void gemm_bt(const u16* __restrict__ A, const u16* __restrict__ Bt,
             int M, int N, int K,
             float* __restrict__ Cf, const float* __restrict__ bias,
             __bf16* __restrict__ qtb, __bf16* __restrict__ ktb,
             __bf16* __restrict__ vtb) {
    __shared__ __align__(16) u16 As[4][64][32];
    __shared__ __align__(16) u16 Bs[4][128][32];
    const int tid = threadIdx.x, w = tid >> 6, lane = tid & 63;
    const int l15 = lane & 15, l4 = lane >> 4;
    const int wr = (w >> 1) * 32, wc = (w & 1) * 64;
    const int bm = blockIdx.y * 64, bn = blockIdx.x * 128;

    f4 acc[2][4];
    #pragma unroll
    for (int i = 0; i < 2; i++)
        #pragma unroll
        for (int j = 0; j < 4; j++) acc[i][j] = (f4){0.f, 0.f, 0.f, 0.f};

    const int rS = lane >> 2;          // row within a 16-row staging group
    const int cS = (lane & 3) * 8;     // col (u16) within the 32-wide row

    for (int k0 = 0; k0 < K; k0 += 128) {
        #pragma unroll
        for (int ks = 0; ks < 4; ks++) {
            // A: sub-tile ks, rows [w*16, +16)
            gl_lds16(A + (size_t)(bm + w * 16 + rS) * K + k0 + ks * 32 + cS,
                     &As[ks][w * 16][0]);
            // B: sub-tile ks, rows [w*32, +16) and [w*32+16, +16)
            gl_lds16(Bt + (size_t)(bn + w * 32 + rS) * K + k0 + ks * 32 + cS,
                     &Bs[ks][w * 32][0]);
            gl_lds16(Bt + (size_t)(bn + w * 32 + 16 + rS) * K + k0 + ks * 32 + cS,
                     &Bs[ks][w * 32 + 16][0]);
        }
        __syncthreads();
        #pragma unroll
        for (int ks = 0; ks < 4; ks++) {
            bf8 af[2], bf[4];
            #pragma unroll
            for (int i = 0; i < 2; i++)
                af[i] = *(const bf8*)&As[ks][wr + i * 16 + l15][l4 * 8];
            #pragma unroll
            for (int j = 0; j < 4; j++)
                bf[j] = *(const bf8*)&Bs[ks][wc + j * 16 + l15][l4 * 8];
            #pragma unroll
            for (int i = 0; i < 2; i++)
                #pragma unroll
                for (int j = 0; j < 4; j++)
                    acc[i][j] = MFMA16(af[i], bf[j], acc[i][j]);
        }
        __syncthreads();
    }
    #pragma unroll
    for (int i = 0; i < 2; i++)
        #pragma unroll
        for (int j = 0; j < 4; j++) {
            const int col = bn + wc + j * 16 + l15;
            const int row0 = bm + wr + i * 16 + l4 * 4;
            if (Cf) {
                #pragma unroll
                for (int reg = 0; reg < 4; reg++)
                    Cf[(size_t)(row0 + reg) * N + col] = acc[i][j][reg] + bias[col];
            } else if (col < 512) {
                int h = col >> 6, d = col & 63;
                #pragma unroll
                for (int reg = 0; reg < 4; reg++) {
                    int row = row0 + reg;
                    int b = row >> 10, t = row & 1023;
                    qtb[((((size_t)(b * 8 + h)) << 10 | t) << 6) | d] =
                        (__bf16)(acc[i][j][reg] * QSC);
                }
            } else if (col < 1024) {
                int h = (col >> 6) - 8, d = col & 63;
                #pragma unroll
                for (int reg = 0; reg < 4; reg++) {
                    int row = row0 + reg;
                    int b = row >> 10, t = row & 1023;
                    ktb[((((size_t)(b * 8 + h)) << 10 | t) << 6) | d] =
                        (__bf16)acc[i][j][reg];
                }
            } else {
                int h = (col >> 6) - 16, d = col & 63;
                int b = row0 >> 10, t = row0 & 1023;   // 4 rows share b (t aligned 4)
                __bf16 pk[4];
                #pragma unroll
                for (int reg = 0; reg < 4; reg++) pk[reg] = (__bf16)acc[i][j][reg];
                *(ushort4*)&vtb[(((size_t)(b * 8 + h) * 64 + d) << 10) | t] =
                    *(ushort4*)pk;
            }
        }
}

// ---------------------------------------------------------------------------
// Fused MFMA flash attention — software-pipelined, ONE barrier per K-tile.
// LDS-pipe traffic was the bottleneck (28 KB/wave-iter; MfmaUtil 10%,
// VALUBusy 30%, HBM 3% => no counted pipe saturated, LDS pipe was).
// Rebalance across pipes:
//  - K stays LDS-staged (double-buffered, register-prefetch, 1 barrier/iter).
//  - V is read DIRECTLY from global (L2-resident per-XCD; vf prefetched into
//    regs right after QK^T so ~L2 latency hides under softmax). Drops Vb
//    (18 KB LDS) + 8 KB/wave-iter LDS reads + commits onto the idle L1 pipe.
//  - Ps is XOR-swizzled: col ^= ((row>>2)&3)<<4. The b16 C-frag writes were
//    ~4-way bank conflicts (l4 groups 0/2 and 1/3 aliased; row stride 144 B
//    == 16 dwords mod 32); swizzle puts the four l4 groups in disjoint bank
//    octets. b128 read-back stays 16B-aligned and 2-way (free).
// No-max softmax (scores tiny): p = exp2(s + qd), l accumulated as per-lane
// partials, reduced once at end. Grid: x = bh (XCD L2 locality), y = s0/64.
// LDS = 45,056 B.
// ---------------------------------------------------------------------------
__global__ __launch_bounds__(256)
void attn_mfma(const u16* __restrict__ qtb, const u16* __restrict__ ktb,
               const u16* __restrict__ vtb, const u16* __restrict__ pembb,
               __bf16* __restrict__ ctxb) {
    __shared__ __align__(16) __bf16 Kb[2][64][72];  // K tiles [t][d]
    __shared__ __align__(16) __bf16 Ps[64][72];     // P tile [s][t] (swizzled)
    __shared__ __align__(16) __bf16 Qd[64][136];    // qdot ring [s][j&127]

    const int tid = threadIdx.x, w = tid >> 6, lane = tid & 63;
    const int l15 = lane & 15, l4 = lane >> 4;
    const int bh = blockIdx.x, b = bh >> 3;
    const int s0 = blockIdx.y * 64;

    // Ps column swizzle terms: element (row, t) lives at col t ^ X(row),
    // X(row) = ((row>>2)&3)<<4. Writes: row = w*16+l4*4+reg -> X = l4<<4.
    // Reads: row = w*16+l15 -> X = (l15>>2)<<4.
    const int xw = l4 << 4;
    const int xr = (l15 >> 2) << 4;

    // Q A-frags from packed qtb (pre-scaled by QSC in the projection GEMM)
    const u16* qp = qtb + ((size_t)bh * SEQ + s0 + w * 16 + l15) * HD + l4 * 8;
    bf8 qa0 = *(const bf8*)qp;
    bf8 qa1 = *(const bf8*)(qp + 32);

    // ---- init ring: j in [s0+449, +127], direct global pemb frags ----
    #pragma unroll
    for (int pass = 0; pass < 2; pass++) {
        const int jlo = s0 + 449 + pass * 64;
        #pragma unroll
        for (int jt = 0; jt < 4; jt++) {
            int jc = min(1024, max(0, jlo + jt * 16 + l15));
            const u16* pp = pembb + (size_t)jc * HD + l4 * 8;
            bf8 b0 = *(const bf8*)pp;
            bf8 b1 = *(const bf8*)(pp + 32);
            f4 f = (f4){0.f, 0.f, 0.f, 0.f};
            f = MFMA16(qa0, b0, f);
            f = MFMA16(qa1, b1, f);
            int sl = w * 16 + l4 * 4;
            int j = jlo + jt * 16 + l15;
            #pragma unroll
            for (int reg = 0; reg < 4; reg++)
                Qd[sl + reg][j & 127] = (__bf16)f[reg];
        }
    }
    asm volatile("" ::: "memory");

    float l_r[4] = {0.f, 0.f, 0.f, 0.f};
    f4 o[4];
    #pragma unroll
    for (int dt = 0; dt < 4; dt++) o[dt] = (f4){0.f, 0.f, 0.f, 0.f};

    const u16* kbase = ktb + (size_t)bh * SEQ * HD;   // [t][d] packed
    const u16* vbase = vtb + (size_t)bh * HD * SEQ;   // [d][t]
    const u16* pbase = pembb + l4 * 8;

    // thread's K staging slots: rows sr and sr+32, 16B at col sc
    const int sr = tid >> 3, sc = (tid & 7) * 8;

    // ---- stage K tile 0 into buf 0 ----
    *(bf8*)&Kb[0][sr][sc]      = *(const bf8*)(kbase + (size_t)sr * HD + sc);
    *(bf8*)&Kb[0][sr + 32][sc] = *(const bf8*)(kbase + (size_t)(sr + 32) * HD + sc);
    __syncthreads();

    for (int i = 0; i < 16; i++) {
        const int cur = i & 1, nxt = cur ^ 1;
        const int t0 = i * 64, t1 = t0 + 64;
        const bool pre = (i < 15);
        // ---- issue next K tile + pemb loads into regs (land this iter) ----
        bf8 kr0, kr1, pb0[4], pb1[4];
        const int jlo_next = s0 + 449 - 64 * (i + 1);
        if (pre) {
            kr0 = *(const bf8*)(kbase + (size_t)(t1 + sr) * HD + sc);
            kr1 = *(const bf8*)(kbase + (size_t)(t1 + sr + 32) * HD + sc);
            #pragma unroll
            for (int jt = 0; jt < 4; jt++) {
                int jc = min(1024, max(0, jlo_next + jt * 16 + l15));
                const u16* pp = pbase + (size_t)jc * HD;
                pb0[jt] = *(const bf8*)pp;
                pb1[jt] = *(const bf8*)(pp + 32);
            }
        }

        // ---- QK^T from Kb[cur] ----
        f4 s[4];
        #pragma unroll
        for (int jt = 0; jt < 4; jt++) {
            bf8 b0 = *(const bf8*)&Kb[cur][jt * 16 + l15][l4 * 8];
            bf8 b1 = *(const bf8*)&Kb[cur][jt * 16 + l15][32 + l4 * 8];
            f4 acc = (f4){0.f, 0.f, 0.f, 0.f};
            acc = MFMA16(qa0, b0, acc);
            acc = MFMA16(qa1, b1, acc);
            s[jt] = acc;
        }
        // ---- V frag prefetch: direct global (L2), hides under softmax ----
        bf8 vf[4][2];
        #pragma unroll
        for (int dt = 0; dt < 4; dt++) {
            const u16* vp = vbase + (size_t)(dt * 16 + l15) * SEQ + t0 + l4 * 8;
            vf[dt][0] = *(const bf8*)vp;
            vf[dt][1] = *(const bf8*)(vp + 32);
        }
        // ---- pos gather + exp2 + l partials ----
        const int jbase = s0 - t0 + 512;
        float sc4[4][4];
        #pragma unroll
        for (int jt = 0; jt < 4; jt++) {
            int tl = jt * 16 + l15;
            #pragma unroll
            for (int reg = 0; reg < 4; reg++) {
                int sl = w * 16 + l4 * 4 + reg;
                int j = jbase + sl - tl;
                float p = fexp2(s[jt][reg] + (float)Qd[sl][j & 127]);
                sc4[jt][reg] = p;
                l_r[reg] += p;
            }
        }
        // ---- P -> Ps (wave-private rows, swizzled), read back as A-frags ----
        #pragma unroll
        for (int jt = 0; jt < 4; jt++)
            #pragma unroll
            for (int reg = 0; reg < 4; reg++)
                Ps[w * 16 + l4 * 4 + reg][(jt * 16 + l15) ^ xw] =
                    (__bf16)sc4[jt][reg];
        asm volatile("" ::: "memory");
        bf8 pa0 = *(const bf8*)&Ps[w * 16 + l15][(l4 * 8) ^ xr];
        bf8 pa1 = *(const bf8*)&Ps[w * 16 + l15][(32 + l4 * 8) ^ xr];
        // ---- PV from prefetched V regs ----
        #pragma unroll
        for (int dt = 0; dt < 4; dt++) {
            o[dt] = MFMA16(pa0, vf[dt][0], o[dt]);
            o[dt] = MFMA16(pa1, vf[dt][1], o[dt]);
        }
        // ---- qdot refresh for next window (pemb frags already in regs) ----
        if (pre) {
            #pragma unroll
            for (int jt = 0; jt < 4; jt++) {
                f4 f = (f4){0.f, 0.f, 0.f, 0.f};
                f = MFMA16(qa0, pb0[jt], f);
                f = MFMA16(qa1, pb1[jt], f);
                int j = jlo_next + jt * 16 + l15;
                #pragma unroll
                for (int reg = 0; reg < 4; reg++)
                    Qd[w * 16 + l4 * 4 + reg][j & 127] = (__bf16)f[reg];
            }
            // ---- commit prefetched K tile to buf nxt ----
            *(bf8*)&Kb[nxt][sr][sc]      = kr0;
            *(bf8*)&Kb[nxt][sr + 32][sc] = kr1;
        }
        __syncthreads();   // single barrier: K staging visible, buffer released
    }
    // ---- epilogue: single l reduction, normalize, store ----
    #pragma unroll
    for (int reg = 0; reg < 4; reg++) {
        float r2 = l_r[reg];
        #pragma unroll
        for (int off = 8; off; off >>= 1) r2 += __shfl_xor(r2, off);
        l_r[reg] = 1.f / r2;
    }
    const int h = bh & 7;
    #pragma unroll
    for (int dt = 0; dt < 4; dt++)
        #pragma unroll
        for (int reg = 0; reg < 4; reg++) {
            int srow = s0 + w * 16 + l4 * 4 + reg;
            float v = o[dt][reg] * l_r[reg];
            ctxb[(size_t)(b * SEQ + srow) * DM + h * HD + dt * 16 + l15] = (__bf16)v;
        }
}

// ---------------------------------------------------------------------------
extern "C" void kernel_launch(void* const* d_in, const int* in_sizes, int n_in,
                              void* d_out, int out_size, void* d_ws, size_t ws_size,
                              hipStream_t stream) {
    const float* x    = (const float*)d_in[0];
    // d_in[1] attn_mask: unused by the reference computation
    const float* Wq   = (const float*)d_in[2];
    const float* Wkv  = (const float*)d_in[3];
    const float* Wout = (const float*)d_in[4];
    const float* bout = (const float*)d_in[5];
    const float* pemb = (const float*)d_in[6];
    float* out = (float*)d_out;

    const int M = BATCH * SEQ;   // 4096
    u16* p = (u16*)d_ws;
    u16* xb    = p; p += (size_t)M * DM;          // 4096x512
    u16* qkvw  = p; p += (size_t)NQKV * DM;       // 1536x512 (Wq^T ++ Wkv^T)
    u16* Woutt = p; p += (size_t)DM * DM;         // 512x512
    u16* pembb = p; p += (size_t)1025 * HD;       // 1025x64
    u16* qtb   = p; p += (size_t)M * DM;          // 32x1024x64 packed q (scaled)
    u16* ktb   = p; p += (size_t)M * DM;          // 32x1024x64 packed K
    u16* vtb   = p; p += (size_t)M * DM;          // 32x64x1024 transposed V
    u16* ctxb  = p; p += (size_t)M * DM;          // 4096x512

    prep<<<3137, 256, 0, stream>>>(x, Wq, Wkv, Wout, pemb, xb, qkvw, Woutt, pembb);

    // QKV projection with fused q-scale / K-pack / V-transpose epilogue
    gemm_bt<<<dim3(NQKV / 128, M / 64), 256, 0, stream>>>(
        xb, qkvw, M, NQKV, DM, nullptr, nullptr,
        (__bf16*)qtb, (__bf16*)ktb, (__bf16*)vtb);

    // fused attention -> ctx; grid x=bh for XCD L2 locality
    attn_mfma<<<dim3(BATCH * NH, SEQ / 64), 256, 0, stream>>>(
        qtb, ktb, vtb, pembb, (__bf16*)ctxb);

    // out = ctx @ Wout + bout
    gemm_bt<<<dim3(DM / 128, M / 64), 256, 0, stream>>>(
        ctxb, Woutt, M, DM, DM, out, bout, nullptr, nullptr, nullptr);
}

// Round 2
// 137.162 us; speedup vs baseline: 1.1370x; 1.1370x over previous
//
#include <hip/hip_runtime.h>
#include <hip/hip_bf16.h>

constexpr int BATCH = 4;
constexpr int SEQ   = 1024;
constexpr int DM    = 512;     // model dim = HEADS*HDIM
constexpr int NH    = 8;
constexpr int HD    = 64;
constexpr int NQKV  = 1536;    // q(512) + k(512) + v(512) fused projection width

typedef unsigned short u16;
typedef __attribute__((ext_vector_type(8))) __bf16 bf8;
typedef __attribute__((ext_vector_type(4))) __bf16 bf4;
typedef __attribute__((ext_vector_type(4))) float  f4;

#define MFMA16(a, b, c) __builtin_amdgcn_mfma_f32_16x16x32_bf16(a, b, c, 0, 0, 0)

// 0.125 (1/sqrt(64)) * log2(e): q pre-scale so softmax uses exp2 directly
#define QSC 0.18033688f

static __device__ __forceinline__ u16 f2b(float f) {
    union { float f; unsigned u; } v; v.f = f;
    unsigned r = v.u + 0x7FFFu + ((v.u >> 16) & 1u);   // RNE; inputs never NaN
    return (u16)(r >> 16);
}
static __device__ __forceinline__ float fexp2(float x) {
    return __builtin_amdgcn_exp2f(x);
}
// async global->LDS, 16 B per lane (dst = wave-uniform base + lane*16)
static __device__ __forceinline__ void gl_lds16(const void* g, void* l) {
    __builtin_amdgcn_global_load_lds(
        (const __attribute__((address_space(1))) void*)g,
        (__attribute__((address_space(3))) void*)l, 16, 0, 0);
}

// ---------------------------------------------------------------------------
// Fused prep: one launch does all fp32->bf16 converts + weight transposes.
// ---------------------------------------------------------------------------
__device__ __forceinline__ void tcvt_tile(const float* __restrict__ in,
                                          u16* __restrict__ out,
                                          int R, int C, int bx, int by, int tid,
                                          float (*t)[33]) {
    int r0 = by * 32, c0 = bx * 32;
    int lc = tid & 31, lr = tid >> 5;   // lr in [0,8)
    #pragma unroll
    for (int p = 0; p < 4; p++) {
        int r = lr + p * 8;
        t[r][lc] = in[(size_t)(r0 + r) * C + c0 + lc];
    }
    __syncthreads();
    #pragma unroll
    for (int p = 0; p < 4; p++) {
        int r = lr + p * 8;
        out[(size_t)(c0 + r) * R + r0 + lc] = f2b(t[lc][r]);
    }
}

__global__ __launch_bounds__(256)
void prep(const float* __restrict__ x, const float* __restrict__ Wq,
          const float* __restrict__ Wkv, const float* __restrict__ Wout,
          const float* __restrict__ pemb,
          u16* __restrict__ xb, u16* __restrict__ qkvw,
          u16* __restrict__ Woutt, u16* __restrict__ pembb) {
    __shared__ float t[32][33];
    const int blk = blockIdx.x, tid = threadIdx.x;
    if (blk < 2048) {
        int i = (blk * 256 + tid) * 4;
        float4 v = *(const float4*)(x + i);
        ushort4 o = {f2b(v.x), f2b(v.y), f2b(v.z), f2b(v.w)};
        *(ushort4*)(xb + i) = o;
    } else if (blk < 2113) {
        int i = ((blk - 2048) * 256 + tid) * 4;
        if (i < 1025 * HD) {
            float4 v = *(const float4*)(pemb + i);
            ushort4 o = {f2b(v.x), f2b(v.y), f2b(v.z), f2b(v.w)};
            *(ushort4*)(pembb + i) = o;
        }
    } else if (blk < 2369) {
        int l = blk - 2113;
        tcvt_tile(Wq, qkvw, 512, 512, l & 15, l >> 4, tid, t);
    } else if (blk < 2881) {
        int l = blk - 2369;
        tcvt_tile(Wkv, qkvw + 512 * 512, 512, 1024, l & 31, l >> 5, tid, t);
    } else {
        int l = blk - 2881;
        tcvt_tile(Wout, Woutt, 512, 512, l & 15, l >> 4, tid, t);
    }
}

// ---------------------------------------------------------------------------
// MFMA GEMM: C[M,N] = A[M,K] @ Bt[N,K]^T  (bf16 in, fp32 acc)
// 64x128 tile, BK=64 split as 2x BK=32 sub-tiles so LDS rows stay 32 u16
// wide (m97 layout: 8-way max aliasing on ds_read_b128; a single [..][64]
// row would be 16-way). 256 threads = 4 waves.  [reverted to the R0 version:
// BK=128 measured ~neutral-to-worse]
// Mode 1 (Cf!=null): fp32 out + bias (the output projection).
// Mode 2 (qtb/ktb/vtb): QKV projection with fused packing —
//   col in [0,512)    -> qtb[bh][s][d], scaled by QSC
//   col in [512,1024) -> ktb[bh][t][d]
//   col in [1024,*)   -> vtb[bh][d][t]  (transposed, ushort4-packed stores)
// ---------------------------------------------------------------------------
__global__ __launch_bounds__(256)
void gemm_bt(const u16* __restrict__ A, const u16* __restrict__ Bt,
             int M, int N, int K,
             float* __restrict__ Cf, const float* __restrict__ bias,
             __bf16* __restrict__ qtb, __bf16* __restrict__ ktb,
             __bf16* __restrict__ vtb) {
    __shared__ __align__(16) u16 As[2][64][32];
    __shared__ __align__(16) u16 Bs[2][128][32];
    const int tid = threadIdx.x, w = tid >> 6, lane = tid & 63;
    const int l15 = lane & 15, l4 = lane >> 4;
    const int wr = (w >> 1) * 32, wc = (w & 1) * 64;
    const int bm = blockIdx.y * 64, bn = blockIdx.x * 128;

    f4 acc[2][4];
    #pragma unroll
    for (int i = 0; i < 2; i++)
        #pragma unroll
        for (int j = 0; j < 4; j++) acc[i][j] = (f4){0.f, 0.f, 0.f, 0.f};

    const int rS = lane >> 2;          // row within a 16-row staging group
    const int cS = (lane & 3) * 8;     // col (u16) within the 32-wide row

    for (int k0 = 0; k0 < K; k0 += 64) {
        #pragma unroll
        for (int ks = 0; ks < 2; ks++) {
            // A: sub-tile ks, rows [w*16, +16)
            gl_lds16(A + (size_t)(bm + w * 16 + rS) * K + k0 + ks * 32 + cS,
                     &As[ks][w * 16][0]);
            // B: sub-tile ks, rows [w*32, +16) and [w*32+16, +16)
            gl_lds16(Bt + (size_t)(bn + w * 32 + rS) * K + k0 + ks * 32 + cS,
                     &Bs[ks][w * 32][0]);
            gl_lds16(Bt + (size_t)(bn + w * 32 + 16 + rS) * K + k0 + ks * 32 + cS,
                     &Bs[ks][w * 32 + 16][0]);
        }
        __syncthreads();
        #pragma unroll
        for (int ks = 0; ks < 2; ks++) {
            bf8 af[2], bf[4];
            #pragma unroll
            for (int i = 0; i < 2; i++)
                af[i] = *(const bf8*)&As[ks][wr + i * 16 + l15][l4 * 8];
            #pragma unroll
            for (int j = 0; j < 4; j++)
                bf[j] = *(const bf8*)&Bs[ks][wc + j * 16 + l15][l4 * 8];
            #pragma unroll
            for (int i = 0; i < 2; i++)
                #pragma unroll
                for (int j = 0; j < 4; j++)
                    acc[i][j] = MFMA16(af[i], bf[j], acc[i][j]);
        }
        __syncthreads();
    }
    #pragma unroll
    for (int i = 0; i < 2; i++)
        #pragma unroll
        for (int j = 0; j < 4; j++) {
            const int col = bn + wc + j * 16 + l15;
            const int row0 = bm + wr + i * 16 + l4 * 4;
            if (Cf) {
                #pragma unroll
                for (int reg = 0; reg < 4; reg++)
                    Cf[(size_t)(row0 + reg) * N + col] = acc[i][j][reg] + bias[col];
            } else if (col < 512) {
                int h = col >> 6, d = col & 63;
                #pragma unroll
                for (int reg = 0; reg < 4; reg++) {
                    int row = row0 + reg;
                    int b = row >> 10, t = row & 1023;
                    qtb[((((size_t)(b * 8 + h)) << 10 | t) << 6) | d] =
                        (__bf16)(acc[i][j][reg] * QSC);
                }
            } else if (col < 1024) {
                int h = (col >> 6) - 8, d = col & 63;
                #pragma unroll
                for (int reg = 0; reg < 4; reg++) {
                    int row = row0 + reg;
                    int b = row >> 10, t = row & 1023;
                    ktb[((((size_t)(b * 8 + h)) << 10 | t) << 6) | d] =
                        (__bf16)acc[i][j][reg];
                }
            } else {
                int h = (col >> 6) - 16, d = col & 63;
                int b = row0 >> 10, t = row0 & 1023;   // 4 rows share b (t aligned 4)
                __bf16 pk[4];
                #pragma unroll
                for (int reg = 0; reg < 4; reg++) pk[reg] = (__bf16)acc[i][j][reg];
                *(ushort4*)&vtb[(((size_t)(b * 8 + h) * 64 + d) << 10) | t] =
                    *(ushort4*)pk;
            }
        }
}

// ---------------------------------------------------------------------------
// Fused MFMA flash attention — software-pipelined, ONE barrier per K-tile.
// R1 lesson: latency-bound on the per-iteration serial chain (global-direct V
// regressed 47.9->65.2us; occupancy is grid-capped at 8 waves/CU). This round
// shortens the chain, keeping R0's sync structure exactly:
//  - K/V double-buffered in LDS, register-prefetch one full iteration ahead.
//  - Ps XOR-swizzled (col ^= ((row>>2)&3)<<4): kills the ~4-way bank conflict
//    on the P round-trip that sits between softmax and PV.
//  - Qd ring TRANSPOSED to [j&127][s]: the 4 acc regs of each refresh MFMA are
//    4 consecutive u16 at one row -> one ds_write_b64 (refresh 16->4 instrs,
//    init 32->8). Wave-privacy preserved: each wave writes/reads only cols
//    [w*16, +16). Gather stays 16 scalar reads (diagonal, inherent).
//  - Vb fragment reads hoisted ABOVE the Ps fence into regs: the compiler
//    can't move them across the asm clobber, so in R0 they serialized behind
//    the Ps write->read round-trip; now their latency hides under exp2.
// No-max softmax (scores tiny): p = exp2(s + qd), l accumulated as per-lane
// partials, reduced once at end. Grid: x = bh (XCD L2 locality), y = s0/64.
// LDS = 64,512 B -> 2 blocks/CU (grid-limited anyway).
// ---------------------------------------------------------------------------
__global__ __launch_bounds__(256)
void attn_mfma(const u16* __restrict__ qtb, const u16* __restrict__ ktb,
               const u16* __restrict__ vtb, const u16* __restrict__ pembb,
               __bf16* __restrict__ ctxb) {
    __shared__ __align__(16) __bf16 Kb[2][64][72];  // K tiles [t][d]
    __shared__ __align__(16) __bf16 Vb[2][64][72];  // V tiles [d][t]
    __shared__ __align__(16) __bf16 Ps[64][72];     // P tile [s][t] (swizzled)
    __shared__ __align__(16) __bf16 Qd[128][72];    // qdot ring [j&127][s]

    const int tid = threadIdx.x, w = tid >> 6, lane = tid & 63;
    const int l15 = lane & 15, l4 = lane >> 4;
    const int bh = blockIdx.x, b = bh >> 3;
    const int s0 = blockIdx.y * 64;

    // Ps column swizzle: element (row, t) lives at col t ^ (((row>>2)&3)<<4).
    // Writes: row = w*16+l4*4+reg -> X = l4<<4. Reads: row = w*16+l15 ->
    // X = (l15>>2)<<4. Each 16B read group has uniform bits>=4 -> stays b128.
    const int xw = l4 << 4;
    const int xr = (l15 >> 2) << 4;

    const int sl0 = w * 16 + l4 * 4;   // this lane's 4-row base in s-local

    // Q A-frags from packed qtb (pre-scaled by QSC in the projection GEMM)
    const u16* qp = qtb + ((size_t)bh * SEQ + s0 + w * 16 + l15) * HD + l4 * 8;
    bf8 qa0 = *(const bf8*)qp;
    bf8 qa1 = *(const bf8*)(qp + 32);

    // ---- init ring: j in [s0+449, +127], direct global pemb frags ----
    #pragma unroll
    for (int pass = 0; pass < 2; pass++) {
        const int jlo = s0 + 449 + pass * 64;
        #pragma unroll
        for (int jt = 0; jt < 4; jt++) {
            int jc = min(1024, max(0, jlo + jt * 16 + l15));
            const u16* pp = pembb + (size_t)jc * HD + l4 * 8;
            bf8 b0 = *(const bf8*)pp;
            bf8 b1 = *(const bf8*)(pp + 32);
            f4 f = (f4){0.f, 0.f, 0.f, 0.f};
            f = MFMA16(qa0, b0, f);
            f = MFMA16(qa1, b1, f);
            int j = jlo + jt * 16 + l15;
            bf4 pk;
            #pragma unroll
            for (int reg = 0; reg < 4; reg++) pk[reg] = (__bf16)f[reg];
            *(bf4*)&Qd[j & 127][sl0] = pk;   // one b64 write (transposed ring)
        }
    }
    asm volatile("" ::: "memory");

    float l_r[4] = {0.f, 0.f, 0.f, 0.f};
    f4 o[4];
    #pragma unroll
    for (int dt = 0; dt < 4; dt++) o[dt] = (f4){0.f, 0.f, 0.f, 0.f};

    const u16* kbase = ktb + (size_t)bh * SEQ * HD;   // [t][d] packed
    const u16* vbase = vtb + (size_t)bh * HD * SEQ;   // [d][t]
    const u16* pbase = pembb + l4 * 8;

    // thread's staging slots: rows r and r+32, 16B at col c
    const int sr = tid >> 3, sc = (tid & 7) * 8;

    // ---- stage tile 0 into buf 0 ----
    *(bf8*)&Kb[0][sr][sc]      = *(const bf8*)(kbase + (size_t)sr * HD + sc);
    *(bf8*)&Kb[0][sr + 32][sc] = *(const bf8*)(kbase + (size_t)(sr + 32) * HD + sc);
    *(bf8*)&Vb[0][sr][sc]      = *(const bf8*)(vbase + (size_t)sr * SEQ + sc);
    *(bf8*)&Vb[0][sr + 32][sc] = *(const bf8*)(vbase + (size_t)(sr + 32) * SEQ + sc);
    __syncthreads();

    for (int i = 0; i < 16; i++) {
        const int cur = i & 1, nxt = cur ^ 1;
        const int t0 = i * 64, t1 = t0 + 64;
        const bool pre = (i < 15);
        // ---- issue next tile's loads into regs (land during this iter) ----
        bf8 kr0, kr1, vr0, vr1, pb0[4], pb1[4];
        const int jlo_next = s0 + 449 - 64 * (i + 1);
        if (pre) {
            kr0 = *(const bf8*)(kbase + (size_t)(t1 + sr) * HD + sc);
            kr1 = *(const bf8*)(kbase + (size_t)(t1 + sr + 32) * HD + sc);
            vr0 = *(const bf8*)(vbase + (size_t)sr * SEQ + t1 + sc);
            vr1 = *(const bf8*)(vbase + (size_t)(sr + 32) * SEQ + t1 + sc);
            #pragma unroll
            for (int jt = 0; jt < 4; jt++) {
                int jc = min(1024, max(0, jlo_next + jt * 16 + l15));
                const u16* pp = pbase + (size_t)jc * HD;
                pb0[jt] = *(const bf8*)pp;
                pb1[jt] = *(const bf8*)(pp + 32);
            }
        }

        // ---- QK^T from Kb[cur] ----
        f4 s[4];
        #pragma unroll
        for (int jt = 0; jt < 4; jt++) {
            bf8 b0 = *(const bf8*)&Kb[cur][jt * 16 + l15][l4 * 8];
            bf8 b1 = *(const bf8*)&Kb[cur][jt * 16 + l15][32 + l4 * 8];
            f4 acc = (f4){0.f, 0.f, 0.f, 0.f};
            acc = MFMA16(qa0, b0, acc);
            acc = MFMA16(qa1, b1, acc);
            s[jt] = acc;
        }
        // ---- V frags: read from LDS NOW (before the Ps fence) so the
        //      ds_read_b128 latency hides under the exp2/softmax chain ----
        bf8 vf0[4], vf1[4];
        #pragma unroll
        for (int dt = 0; dt < 4; dt++) {
            vf0[dt] = *(const bf8*)&Vb[cur][dt * 16 + l15][l4 * 8];
            vf1[dt] = *(const bf8*)&Vb[cur][dt * 16 + l15][32 + l4 * 8];
        }
        // ---- pos gather + exp2 + l partials ----
        const int jbase = s0 - t0 + 512;
        float sc4[4][4];
        #pragma unroll
        for (int jt = 0; jt < 4; jt++) {
            int tl = jt * 16 + l15;
            #pragma unroll
            for (int reg = 0; reg < 4; reg++) {
                int sl = sl0 + reg;
                int j = jbase + sl - tl;
                float p = fexp2(s[jt][reg] + (float)Qd[j & 127][sl]);
                sc4[jt][reg] = p;
                l_r[reg] += p;
            }
        }
        // ---- P -> Ps (wave-private rows, swizzled), read back as A-frags ----
        #pragma unroll
        for (int jt = 0; jt < 4; jt++)
            #pragma unroll
            for (int reg = 0; reg < 4; reg++)
                Ps[sl0 + reg][(jt * 16 + l15) ^ xw] = (__bf16)sc4[jt][reg];
        asm volatile("" ::: "memory");
        bf8 pa0 = *(const bf8*)&Ps[w * 16 + l15][(l4 * 8) ^ xr];
        bf8 pa1 = *(const bf8*)&Ps[w * 16 + l15][(32 + l4 * 8) ^ xr];
        // ---- PV from pre-loaded V frags ----
        #pragma unroll
        for (int dt = 0; dt < 4; dt++) {
            o[dt] = MFMA16(pa0, vf0[dt], o[dt]);
            o[dt] = MFMA16(pa1, vf1[dt], o[dt]);
        }
        // ---- qdot refresh for next window (pemb frags already in regs) ----
        if (pre) {
            #pragma unroll
            for (int jt = 0; jt < 4; jt++) {
                f4 f = (f4){0.f, 0.f, 0.f, 0.f};
                f = MFMA16(qa0, pb0[jt], f);
                f = MFMA16(qa1, pb1[jt], f);
                int j = jlo_next + jt * 16 + l15;
                bf4 pk;
                #pragma unroll
                for (int reg = 0; reg < 4; reg++) pk[reg] = (__bf16)f[reg];
                *(bf4*)&Qd[j & 127][sl0] = pk;   // one b64 write
            }
            // ---- commit prefetched tile to buf nxt ----
            *(bf8*)&Kb[nxt][sr][sc]      = kr0;
            *(bf8*)&Kb[nxt][sr + 32][sc] = kr1;
            *(bf8*)&Vb[nxt][sr][sc]      = vr0;
            *(bf8*)&Vb[nxt][sr + 32][sc] = vr1;
        }
        __syncthreads();   // single barrier: staging visible, buffers released
    }
    // ---- epilogue: single l reduction, normalize, store ----
    #pragma unroll
    for (int reg = 0; reg < 4; reg++) {
        float r2 = l_r[reg];
        #pragma unroll
        for (int off = 8; off; off >>= 1) r2 += __shfl_xor(r2, off);
        l_r[reg] = 1.f / r2;
    }
    const int h = bh & 7;
    #pragma unroll
    for (int dt = 0; dt < 4; dt++)
        #pragma unroll
        for (int reg = 0; reg < 4; reg++) {
            int srow = s0 + w * 16 + l4 * 4 + reg;
            float v = o[dt][reg] * l_r[reg];
            ctxb[(size_t)(b * SEQ + srow) * DM + h * HD + dt * 16 + l15] = (__bf16)v;
        }
}

// ---------------------------------------------------------------------------
extern "C" void kernel_launch(void* const* d_in, const int* in_sizes, int n_in,
                              void* d_out, int out_size, void* d_ws, size_t ws_size,
                              hipStream_t stream) {
    const float* x    = (const float*)d_in[0];
    // d_in[1] attn_mask: unused by the reference computation
    const float* Wq   = (const float*)d_in[2];
    const float* Wkv  = (const float*)d_in[3];
    const float* Wout = (const float*)d_in[4];
    const float* bout = (const float*)d_in[5];
    const float* pemb = (const float*)d_in[6];
    float* out = (float*)d_out;

    const int M = BATCH * SEQ;   // 4096
    u16* p = (u16*)d_ws;
    u16* xb    = p; p += (size_t)M * DM;          // 4096x512
    u16* qkvw  = p; p += (size_t)NQKV * DM;       // 1536x512 (Wq^T ++ Wkv^T)
    u16* Woutt = p; p += (size_t)DM * DM;         // 512x512
    u16* pembb = p; p += (size_t)1025 * HD;       // 1025x64
    u16* qtb   = p; p += (size_t)M * DM;          // 32x1024x64 packed q (scaled)
    u16* ktb   = p; p += (size_t)M * DM;          // 32x1024x64 packed K
    u16* vtb   = p; p += (size_t)M * DM;          // 32x64x1024 transposed V
    u16* ctxb  = p; p += (size_t)M * DM;          // 4096x512

    prep<<<3137, 256, 0, stream>>>(x, Wq, Wkv, Wout, pemb, xb, qkvw, Woutt, pembb);

    // QKV projection with fused q-scale / K-pack / V-transpose epilogue
    gemm_bt<<<dim3(NQKV / 128, M / 64), 256, 0, stream>>>(
        xb, qkvw, M, NQKV, DM, nullptr, nullptr,
        (__bf16*)qtb, (__bf16*)ktb, (__bf16*)vtb);

    // fused attention -> ctx; grid x=bh for XCD L2 locality
    attn_mfma<<<dim3(BATCH * NH, SEQ / 64), 256, 0, stream>>>(
        qtb, ktb, vtb, pembb, (__bf16*)ctxb);

    // out = ctx @ Wout + bout
    gemm_bt<<<dim3(DM / 128, M / 64), 256, 0, stream>>>(
        ctxb, Woutt, M, DM, DM, out, bout, nullptr, nullptr, nullptr);
}

// Round 3
// 127.252 us; speedup vs baseline: 1.2255x; 1.0779x over previous
//
#include <hip/hip_runtime.h>
#include <hip/hip_bf16.h>

constexpr int BATCH = 4;
constexpr int SEQ   = 1024;
constexpr int DM    = 512;     // model dim = HEADS*HDIM
constexpr int NH    = 8;
constexpr int HD    = 64;
constexpr int NQKV  = 1536;    // q(512) + k(512) + v(512) fused projection width

typedef unsigned short u16;
typedef __attribute__((ext_vector_type(8))) __bf16 bf8;
typedef __attribute__((ext_vector_type(4))) __bf16 bf4;
typedef __attribute__((ext_vector_type(4))) float  f4;
typedef __attribute__((ext_vector_type(16))) float f16v;

#define MFMA16(a, b, c) __builtin_amdgcn_mfma_f32_16x16x32_bf16(a, b, c, 0, 0, 0)
#define MFMA32(a, b, c) __builtin_amdgcn_mfma_f32_32x32x16_bf16(a, b, c, 0, 0, 0)

// 0.125 (1/sqrt(64)) * log2(e): q pre-scale so softmax uses exp2 directly
#define QSC 0.18033688f

static __device__ __forceinline__ u16 f2b(float f) {
    union { float f; unsigned u; } v; v.f = f;
    unsigned r = v.u + 0x7FFFu + ((v.u >> 16) & 1u);   // RNE; inputs never NaN
    return (u16)(r >> 16);
}
static __device__ __forceinline__ float fexp2(float x) {
    return __builtin_amdgcn_exp2f(x);
}
// async global->LDS, 16 B per lane (dst = wave-uniform base + lane*16)
static __device__ __forceinline__ void gl_lds16(const void* g, void* l) {
    __builtin_amdgcn_global_load_lds(
        (const __attribute__((address_space(1))) void*)g,
        (__attribute__((address_space(3))) void*)l, 16, 0, 0);
}
// pack two f32 -> one u32 of 2 bf16 (RNE), single VOP3
static __device__ __forceinline__ unsigned cvtpk_bf16(float lo, float hi) {
    unsigned r;
    asm("v_cvt_pk_bf16_f32 %0, %1, %2" : "=v"(r) : "v"(lo), "v"(hi));
    return r;
}
// swap a's hi-32-lane half with b's lo-32-lane half:
// post: a = {a.lo32, b.lo32}, b = {a.hi32, b.hi32}
static __device__ __forceinline__ void swap32(unsigned &a, unsigned &b) {
    asm("v_permlane32_swap_b32 %0, %1" : "+v"(a), "+v"(b));
}

// ---------------------------------------------------------------------------
// Fused prep: one launch does all fp32->bf16 converts + weight transposes.
// ---------------------------------------------------------------------------
__device__ __forceinline__ void tcvt_tile(const float* __restrict__ in,
                                          u16* __restrict__ out,
                                          int R, int C, int bx, int by, int tid,
                                          float (*t)[33]) {
    int r0 = by * 32, c0 = bx * 32;
    int lc = tid & 31, lr = tid >> 5;   // lr in [0,8)
    #pragma unroll
    for (int p = 0; p < 4; p++) {
        int r = lr + p * 8;
        t[r][lc] = in[(size_t)(r0 + r) * C + c0 + lc];
    }
    __syncthreads();
    #pragma unroll
    for (int p = 0; p < 4; p++) {
        int r = lr + p * 8;
        out[(size_t)(c0 + r) * R + r0 + lc] = f2b(t[lc][r]);
    }
}

__global__ __launch_bounds__(256)
void prep(const float* __restrict__ x, const float* __restrict__ Wq,
          const float* __restrict__ Wkv, const float* __restrict__ Wout,
          const float* __restrict__ pemb,
          u16* __restrict__ xb, u16* __restrict__ qkvw,
          u16* __restrict__ Woutt, u16* __restrict__ pembb) {
    __shared__ float t[32][33];
    const int blk = blockIdx.x, tid = threadIdx.x;
    if (blk < 2048) {
        int i = (blk * 256 + tid) * 4;
        float4 v = *(const float4*)(x + i);
        ushort4 o = {f2b(v.x), f2b(v.y), f2b(v.z), f2b(v.w)};
        *(ushort4*)(xb + i) = o;
    } else if (blk < 2113) {
        int i = ((blk - 2048) * 256 + tid) * 4;
        if (i < 1025 * HD) {
            float4 v = *(const float4*)(pemb + i);
            ushort4 o = {f2b(v.x), f2b(v.y), f2b(v.z), f2b(v.w)};
            *(ushort4*)(pembb + i) = o;
        }
    } else if (blk < 2369) {
        int l = blk - 2113;
        tcvt_tile(Wq, qkvw, 512, 512, l & 15, l >> 4, tid, t);
    } else if (blk < 2881) {
        int l = blk - 2369;
        tcvt_tile(Wkv, qkvw + 512 * 512, 512, 1024, l & 31, l >> 5, tid, t);
    } else {
        int l = blk - 2881;
        tcvt_tile(Wout, Woutt, 512, 512, l & 15, l >> 4, tid, t);
    }
}

// ---------------------------------------------------------------------------
// MFMA GEMM: C[M,N] = A[M,K] @ Bt[N,K]^T  (bf16 in, fp32 acc)
// 64x128 tile, BK=64 split as 2x BK=32 sub-tiles (m97 layout). 4 waves.
// Mode 1 (Cf!=null): fp32 out + bias (the output projection).
// Mode 2 (qtb/ktb/vtb): QKV projection with fused packing —
//   col in [0,512)    -> qtb[bh][s][d], scaled by QSC
//   col in [512,1024) -> ktb[bh][t][d]
//   col in [1024,*)   -> vtb[bh][d][t]  (transposed, ushort4-packed stores)
// ---------------------------------------------------------------------------
__global__ __launch_bounds__(256)
void gemm_bt(const u16* __restrict__ A, const u16* __restrict__ Bt,
             int M, int N, int K,
             float* __restrict__ Cf, const float* __restrict__ bias,
             __bf16* __restrict__ qtb, __bf16* __restrict__ ktb,
             __bf16* __restrict__ vtb) {
    __shared__ __align__(16) u16 As[2][64][32];
    __shared__ __align__(16) u16 Bs[2][128][32];
    const int tid = threadIdx.x, w = tid >> 6, lane = tid & 63;
    const int l15 = lane & 15, l4 = lane >> 4;
    const int wr = (w >> 1) * 32, wc = (w & 1) * 64;
    const int bm = blockIdx.y * 64, bn = blockIdx.x * 128;

    f4 acc[2][4];
    #pragma unroll
    for (int i = 0; i < 2; i++)
        #pragma unroll
        for (int j = 0; j < 4; j++) acc[i][j] = (f4){0.f, 0.f, 0.f, 0.f};

    const int rS = lane >> 2;          // row within a 16-row staging group
    const int cS = (lane & 3) * 8;     // col (u16) within the 32-wide row

    for (int k0 = 0; k0 < K; k0 += 64) {
        #pragma unroll
        for (int ks = 0; ks < 2; ks++) {
            gl_lds16(A + (size_t)(bm + w * 16 + rS) * K + k0 + ks * 32 + cS,
                     &As[ks][w * 16][0]);
            gl_lds16(Bt + (size_t)(bn + w * 32 + rS) * K + k0 + ks * 32 + cS,
                     &Bs[ks][w * 32][0]);
            gl_lds16(Bt + (size_t)(bn + w * 32 + 16 + rS) * K + k0 + ks * 32 + cS,
                     &Bs[ks][w * 32 + 16][0]);
        }
        __syncthreads();
        #pragma unroll
        for (int ks = 0; ks < 2; ks++) {
            bf8 af[2], bf[4];
            #pragma unroll
            for (int i = 0; i < 2; i++)
                af[i] = *(const bf8*)&As[ks][wr + i * 16 + l15][l4 * 8];
            #pragma unroll
            for (int j = 0; j < 4; j++)
                bf[j] = *(const bf8*)&Bs[ks][wc + j * 16 + l15][l4 * 8];
            #pragma unroll
            for (int i = 0; i < 2; i++)
                #pragma unroll
                for (int j = 0; j < 4; j++)
                    acc[i][j] = MFMA16(af[i], bf[j], acc[i][j]);
        }
        __syncthreads();
    }
    #pragma unroll
    for (int i = 0; i < 2; i++)
        #pragma unroll
        for (int j = 0; j < 4; j++) {
            const int col = bn + wc + j * 16 + l15;
            const int row0 = bm + wr + i * 16 + l4 * 4;
            if (Cf) {
                #pragma unroll
                for (int reg = 0; reg < 4; reg++)
                    Cf[(size_t)(row0 + reg) * N + col] = acc[i][j][reg] + bias[col];
            } else if (col < 512) {
                int h = col >> 6, d = col & 63;
                #pragma unroll
                for (int reg = 0; reg < 4; reg++) {
                    int row = row0 + reg;
                    int b = row >> 10, t = row & 1023;
                    qtb[((((size_t)(b * 8 + h)) << 10 | t) << 6) | d] =
                        (__bf16)(acc[i][j][reg] * QSC);
                }
            } else if (col < 1024) {
                int h = (col >> 6) - 8, d = col & 63;
                #pragma unroll
                for (int reg = 0; reg < 4; reg++) {
                    int row = row0 + reg;
                    int b = row >> 10, t = row & 1023;
                    ktb[((((size_t)(b * 8 + h)) << 10 | t) << 6) | d] =
                        (__bf16)acc[i][j][reg];
                }
            } else {
                int h = (col >> 6) - 16, d = col & 63;
                int b = row0 >> 10, t = row0 & 1023;   // 4 rows share b (t aligned 4)
                __bf16 pk[4];
                #pragma unroll
                for (int reg = 0; reg < 4; reg++) pk[reg] = (__bf16)acc[i][j][reg];
                *(ushort4*)&vtb[(((size_t)(b * 8 + h) * 64 + d) << 10) | t] =
                    *(ushort4*)pk;
            }
        }
}

// ---------------------------------------------------------------------------
// Fused MFMA flash attention — 32x32 quadrant restructure (T12 port).
// R2 LDS ledger was ~474 cy/wave-iter (K 96 + V 96 + ring 93 + Ps RT 117 +
// writes 72); all 4 waves redundantly read the full K/V tiles, and P took an
// LDS round-trip. New structure (4 waves = 2(q) x 2(t) quadrants):
//  - Swapped QK^T (mfma32(K, Q)): output col = lane&31 = q -> softmax is
//    lane-local; row = t = wt*32 + (reg&3)+8*(reg>>2)+4*(lane>>5).
//  - P -> PV A-frags IN REGISTERS: 8 v_cvt_pk_bf16_f32 + 4 permlane32_swap
//    (lane keeps its q; halves exchange t-octets). Ps buffer + fence GONE.
//  - Each wave reads only its wt-half of K (4 b128) and contracts PV over
//    that half (V 4 b128); partial O reduced across wave pairs once at end
//    through reused ring LDS.
//  - Ring Qd[256][72] ([j&255][s]): 256 slots so same-iter cross-wave
//    write/read windows never alias mod ring size (2 waves share q-rows now).
//    Writes b64 (refresh output col = j), reads scalar (diagonal, inherent).
// LDS ledger: 48+48+93+24+48 = ~261 cy/wave-iter (-45%). One barrier/iter.
// Grid: x = bh (XCD L2 locality), y = s0/64. LDS = 73,728 B -> 2 blocks/CU.
// ---------------------------------------------------------------------------
__global__ __launch_bounds__(256)
void attn_mfma(const u16* __restrict__ qtb, const u16* __restrict__ ktb,
               const u16* __restrict__ vtb, const u16* __restrict__ pembb,
               __bf16* __restrict__ ctxb) {
    __shared__ __align__(16) __bf16 Kb[2][64][72];  // K tiles [t][d]
    __shared__ __align__(16) __bf16 Vb[2][64][72];  // V tiles [d][t]
    __shared__ __align__(16) __bf16 Qd[256][72];    // qdot ring [j&255][s]

    const int tid = threadIdx.x, w = tid >> 6, lane = tid & 63;
    const int l31 = lane & 31, hi = lane >> 5;
    const int wq = w >> 1, wt = w & 1;
    const int bh = blockIdx.x, b = bh >> 3;
    const int s0 = blockIdx.y * 64;

    // Q frags (B-operand for swapped QK^T, A-operand for ring refresh):
    // rows s0 + wq*32 + l31, k-elems d = st*16 + hi*8 .. +8
    bf8 qb[4];
    {
        const u16* qp = qtb + ((size_t)bh * SEQ + s0 + wq * 32 + l31) * HD + hi * 8;
        #pragma unroll
        for (int st = 0; st < 4; st++) qb[st] = *(const bf8*)(qp + st * 16);
    }

    // ---- init ring: j in [s0+449, +127], wave covers (s=wq-half, j=wt-half)
    #pragma unroll
    for (int pass = 0; pass < 2; pass++) {
        const int jr = s0 + 449 + pass * 64 + wt * 32 + l31;
        const int jc = min(1024, max(0, jr));
        const u16* pp = pembb + (size_t)jc * HD + hi * 8;
        f16v acc;
        #pragma unroll
        for (int r = 0; r < 16; r++) acc[r] = 0.f;
        #pragma unroll
        for (int st = 0; st < 4; st++) {
            bf8 pj = *(const bf8*)(pp + st * 16);
            acc = MFMA32(qb[st], pj, acc);
        }
        #pragma unroll
        for (int o4 = 0; o4 < 4; o4++) {
            bf4 pk;
            #pragma unroll
            for (int r = 0; r < 4; r++) pk[r] = (__bf16)acc[o4 * 4 + r];
            *(bf4*)&Qd[jr & 255][wq * 32 + o4 * 8 + hi * 4] = pk;
        }
    }

    float l_lane = 0.f;
    f16v oo[2];
    #pragma unroll
    for (int dt = 0; dt < 2; dt++)
        #pragma unroll
        for (int r = 0; r < 16; r++) oo[dt][r] = 0.f;

    const u16* kbase = ktb + (size_t)bh * SEQ * HD;   // [t][d] packed
    const u16* vbase = vtb + (size_t)bh * HD * SEQ;   // [d][t]
    const int sr = tid >> 3, sc = (tid & 7) * 8;

    // ---- stage tile 0 into buf 0 ----
    *(bf8*)&Kb[0][sr][sc]      = *(const bf8*)(kbase + (size_t)sr * HD + sc);
    *(bf8*)&Kb[0][sr + 32][sc] = *(const bf8*)(kbase + (size_t)(sr + 32) * HD + sc);
    *(bf8*)&Vb[0][sr][sc]      = *(const bf8*)(vbase + (size_t)sr * SEQ + sc);
    *(bf8*)&Vb[0][sr + 32][sc] = *(const bf8*)(vbase + (size_t)(sr + 32) * SEQ + sc);
    __syncthreads();

    for (int i = 0; i < 16; i++) {
        const int cur = i & 1, nxt = cur ^ 1;
        const int t0 = i * 64, t1 = t0 + 64;
        const bool pre = (i < 15);
        bf8 kr0, kr1, vr0, vr1, pj0, pj1, pj2, pj3;
        const int jrn = s0 + 449 - 64 * (i + 1) + wt * 32 + l31;
        if (pre) {
            kr0 = *(const bf8*)(kbase + (size_t)(t1 + sr) * HD + sc);
            kr1 = *(const bf8*)(kbase + (size_t)(t1 + sr + 32) * HD + sc);
            vr0 = *(const bf8*)(vbase + (size_t)sr * SEQ + t1 + sc);
            vr1 = *(const bf8*)(vbase + (size_t)(sr + 32) * SEQ + t1 + sc);
            const int jc = min(1024, max(0, jrn));
            const u16* pp = pembb + (size_t)jc * HD + hi * 8;
            pj0 = *(const bf8*)(pp);
            pj1 = *(const bf8*)(pp + 16);
            pj2 = *(const bf8*)(pp + 32);
            pj3 = *(const bf8*)(pp + 48);
        }

        // ---- QK^T, swapped: lane holds q = wq*32+l31, 16 t's of wt-half ----
        f16v s16;
        #pragma unroll
        for (int r = 0; r < 16; r++) s16[r] = 0.f;
        #pragma unroll
        for (int st = 0; st < 4; st++) {
            bf8 ka = *(const bf8*)&Kb[cur][wt * 32 + l31][st * 16 + hi * 8];
            s16 = MFMA32(ka, qb[st], s16);
        }
        // ---- V frags early (latency hides under softmax) ----
        bf8 vf00 = *(const bf8*)&Vb[cur][l31][wt * 32 + hi * 8];
        bf8 vf01 = *(const bf8*)&Vb[cur][l31][wt * 32 + 16 + hi * 8];
        bf8 vf10 = *(const bf8*)&Vb[cur][32 + l31][wt * 32 + hi * 8];
        bf8 vf11 = *(const bf8*)&Vb[cur][32 + l31][wt * 32 + 16 + hi * 8];

        // ---- ring gather + exp2 + l partials (all lane-local) ----
        const int jcst = (s0 - t0 + 512) + wq * 32 + l31 - wt * 32 - 4 * hi;
        const __bf16* qdc = &Qd[0][wq * 32 + l31];
        float p[16];
        #pragma unroll
        for (int r = 0; r < 16; r++) {
            const int pat = (r & 3) + 8 * (r >> 2);
            const int j = (jcst - pat) & 255;
            float pv = fexp2(s16[r] + (float)qdc[j * 72]);
            p[r] = pv;
            l_lane += pv;
        }
        // ---- pack + permlane32 half-swap -> PV A-frags (no LDS) ----
        unsigned w00 = cvtpk_bf16(p[0],  p[1]),  w01 = cvtpk_bf16(p[2],  p[3]);
        unsigned w10 = cvtpk_bf16(p[4],  p[5]),  w11 = cvtpk_bf16(p[6],  p[7]);
        unsigned w20 = cvtpk_bf16(p[8],  p[9]),  w21 = cvtpk_bf16(p[10], p[11]);
        unsigned w30 = cvtpk_bf16(p[12], p[13]), w31 = cvtpk_bf16(p[14], p[15]);
        swap32(w00, w10); swap32(w01, w11);
        swap32(w20, w30); swap32(w21, w31);
        union { unsigned u[4]; bf8 v; } pa0, pa1;
        pa0.u[0] = w00; pa0.u[1] = w01; pa0.u[2] = w10; pa0.u[3] = w11;
        pa1.u[0] = w20; pa1.u[1] = w21; pa1.u[2] = w30; pa1.u[3] = w31;
        // ---- PV: partial O over this wave's wt t-half ----
        oo[0] = MFMA32(pa0.v, vf00, oo[0]);
        oo[0] = MFMA32(pa1.v, vf01, oo[0]);
        oo[1] = MFMA32(pa0.v, vf10, oo[1]);
        oo[1] = MFMA32(pa1.v, vf11, oo[1]);

        // ---- ring refresh for next window (pemb frags already in regs) ----
        if (pre) {
            f16v rf;
            #pragma unroll
            for (int r = 0; r < 16; r++) rf[r] = 0.f;
            rf = MFMA32(qb[0], pj0, rf);
            rf = MFMA32(qb[1], pj1, rf);
            rf = MFMA32(qb[2], pj2, rf);
            rf = MFMA32(qb[3], pj3, rf);
            #pragma unroll
            for (int o4 = 0; o4 < 4; o4++) {
                bf4 pk;
                #pragma unroll
                for (int r = 0; r < 4; r++) pk[r] = (__bf16)rf[o4 * 4 + r];
                *(bf4*)&Qd[jrn & 255][wq * 32 + o4 * 8 + hi * 4] = pk;
            }
            // ---- commit prefetched K/V tile to buf nxt ----
            *(bf8*)&Kb[nxt][sr][sc]      = kr0;
            *(bf8*)&Kb[nxt][sr + 32][sc] = kr1;
            *(bf8*)&Vb[nxt][sr][sc]      = vr0;
            *(bf8*)&Vb[nxt][sr + 32][sc] = vr1;
        }
        __syncthreads();   // single barrier: staging visible, buffers released
    }

    // ---- epilogue: cross-half l, cross-wave O reduce (ring LDS reused),
    //      normalize, store ----
    float lsum = l_lane + __shfl_xor(l_lane, 32);
    float* Os = (float*)&Qd[0][0];          // ring is dead; reuse as scratch
    float* Ls = Os + 4096;
    if (lane < 32) Ls[(wq * 2 + wt) * 32 + l31] = lsum;
    if (wt == 0) {
        #pragma unroll
        for (int dt = 0; dt < 2; dt++)
            #pragma unroll
            for (int r = 0; r < 16; r++) {
                const int q = (r & 3) + 8 * (r >> 2) + 4 * hi;
                Os[(wq * 32 + q) * 64 + dt * 32 + l31] = oo[dt][r];
            }
    }
    __syncthreads();
    if (wt == 1) {
        const int h = bh & 7;
        #pragma unroll
        for (int r = 0; r < 16; r++) {
            const int q = (r & 3) + 8 * (r >> 2) + 4 * hi;
            const float li = 1.f / (Ls[wq * 64 + q] + Ls[wq * 64 + 32 + q]);
            #pragma unroll
            for (int dt = 0; dt < 2; dt++) {
                float v = (oo[dt][r] + Os[(wq * 32 + q) * 64 + dt * 32 + l31]) * li;
                ctxb[(size_t)(b * SEQ + s0 + wq * 32 + q) * DM + h * HD + dt * 32 + l31]
                    = (__bf16)v;
            }
        }
    }
}

// ---------------------------------------------------------------------------
extern "C" void kernel_launch(void* const* d_in, const int* in_sizes, int n_in,
                              void* d_out, int out_size, void* d_ws, size_t ws_size,
                              hipStream_t stream) {
    const float* x    = (const float*)d_in[0];
    // d_in[1] attn_mask: unused by the reference computation
    const float* Wq   = (const float*)d_in[2];
    const float* Wkv  = (const float*)d_in[3];
    const float* Wout = (const float*)d_in[4];
    const float* bout = (const float*)d_in[5];
    const float* pemb = (const float*)d_in[6];
    float* out = (float*)d_out;

    const int M = BATCH * SEQ;   // 4096
    u16* p = (u16*)d_ws;
    u16* xb    = p; p += (size_t)M * DM;          // 4096x512
    u16* qkvw  = p; p += (size_t)NQKV * DM;       // 1536x512 (Wq^T ++ Wkv^T)
    u16* Woutt = p; p += (size_t)DM * DM;         // 512x512
    u16* pembb = p; p += (size_t)1025 * HD;       // 1025x64
    u16* qtb   = p; p += (size_t)M * DM;          // 32x1024x64 packed q (scaled)
    u16* ktb   = p; p += (size_t)M * DM;          // 32x1024x64 packed K
    u16* vtb   = p; p += (size_t)M * DM;          // 32x64x1024 transposed V
    u16* ctxb  = p; p += (size_t)M * DM;          // 4096x512

    prep<<<3137, 256, 0, stream>>>(x, Wq, Wkv, Wout, pemb, xb, qkvw, Woutt, pembb);

    // QKV projection with fused q-scale / K-pack / V-transpose epilogue
    gemm_bt<<<dim3(NQKV / 128, M / 64), 256, 0, stream>>>(
        xb, qkvw, M, NQKV, DM, nullptr, nullptr,
        (__bf16*)qtb, (__bf16*)ktb, (__bf16*)vtb);

    // fused attention -> ctx; grid x=bh for XCD L2 locality
    attn_mfma<<<dim3(BATCH * NH, SEQ / 64), 256, 0, stream>>>(
        qtb, ktb, vtb, pembb, (__bf16*)ctxb);

    // out = ctx @ Wout + bout
    gemm_bt<<<dim3(DM / 128, M / 64), 256, 0, stream>>>(
        ctxb, Woutt, M, DM, DM, out, bout, nullptr, nullptr, nullptr);
}

// Round 4
// 124.633 us; speedup vs baseline: 1.2513x; 1.0210x over previous
//
#include <hip/hip_runtime.h>
#include <hip/hip_bf16.h>

constexpr int BATCH = 4;
constexpr int SEQ   = 1024;
constexpr int DM    = 512;     // model dim = HEADS*HDIM
constexpr int NH    = 8;
constexpr int HD    = 64;
constexpr int NQKV  = 1536;    // q(512) + k(512) + v(512) fused projection width

typedef unsigned short u16;
typedef __attribute__((ext_vector_type(8))) __bf16 bf8;
typedef __attribute__((ext_vector_type(4))) __bf16 bf4;
typedef __attribute__((ext_vector_type(4))) float  f4;
typedef __attribute__((ext_vector_type(16))) float f16v;

#define MFMA16(a, b, c) __builtin_amdgcn_mfma_f32_16x16x32_bf16(a, b, c, 0, 0, 0)
#define MFMA32(a, b, c) __builtin_amdgcn_mfma_f32_32x32x16_bf16(a, b, c, 0, 0, 0)

// 0.125 (1/sqrt(64)) * log2(e): q pre-scale so softmax uses exp2 directly
#define QSC 0.18033688f

static __device__ __forceinline__ u16 f2b(float f) {
    union { float f; unsigned u; } v; v.f = f;
    unsigned r = v.u + 0x7FFFu + ((v.u >> 16) & 1u);   // RNE; inputs never NaN
    return (u16)(r >> 16);
}
static __device__ __forceinline__ float b2f(u16 x) {
    union { unsigned u; float f; } v; v.u = (unsigned)x << 16;   // bf16->f32 exact
    return v.f;
}
static __device__ __forceinline__ float fexp2(float x) {
    return __builtin_amdgcn_exp2f(x);
}
// async global->LDS, 16 B per lane (dst = wave-uniform base + lane*16)
static __device__ __forceinline__ void gl_lds16(const void* g, void* l) {
    __builtin_amdgcn_global_load_lds(
        (const __attribute__((address_space(1))) void*)g,
        (__attribute__((address_space(3))) void*)l, 16, 0, 0);
}
// pack two f32 -> one u32 of 2 bf16 (RNE), single VOP3
static __device__ __forceinline__ unsigned cvtpk_bf16(float lo, float hi) {
    unsigned r;
    asm("v_cvt_pk_bf16_f32 %0, %1, %2" : "=v"(r) : "v"(lo), "v"(hi));
    return r;
}
// swap a's hi-32-lane half with b's lo-32-lane half
static __device__ __forceinline__ void swap32(unsigned &a, unsigned &b) {
    asm("v_permlane32_swap_b32 %0, %1" : "+v"(a), "+v"(b));
}

// ---------------------------------------------------------------------------
// Fused prep: one launch does all fp32->bf16 converts + weight transposes.
// ---------------------------------------------------------------------------
__device__ __forceinline__ void tcvt_tile(const float* __restrict__ in,
                                          u16* __restrict__ out,
                                          int R, int C, int bx, int by, int tid,
                                          float (*t)[33]) {
    int r0 = by * 32, c0 = bx * 32;
    int lc = tid & 31, lr = tid >> 5;   // lr in [0,8)
    #pragma unroll
    for (int p = 0; p < 4; p++) {
        int r = lr + p * 8;
        t[r][lc] = in[(size_t)(r0 + r) * C + c0 + lc];
    }
    __syncthreads();
    #pragma unroll
    for (int p = 0; p < 4; p++) {
        int r = lr + p * 8;
        out[(size_t)(c0 + r) * R + r0 + lc] = f2b(t[lc][r]);
    }
}

__global__ __launch_bounds__(256)
void prep(const float* __restrict__ x, const float* __restrict__ Wq,
          const float* __restrict__ Wkv, const float* __restrict__ Wout,
          const float* __restrict__ pemb,
          u16* __restrict__ xb, u16* __restrict__ qkvw,
          u16* __restrict__ Woutt, u16* __restrict__ pembb) {
    __shared__ float t[32][33];
    const int blk = blockIdx.x, tid = threadIdx.x;
    if (blk < 2048) {
        int i = (blk * 256 + tid) * 4;
        float4 v = *(const float4*)(x + i);
        ushort4 o = {f2b(v.x), f2b(v.y), f2b(v.z), f2b(v.w)};
        *(ushort4*)(xb + i) = o;
    } else if (blk < 2113) {
        int i = ((blk - 2048) * 256 + tid) * 4;
        if (i < 1025 * HD) {
            float4 v = *(const float4*)(pemb + i);
            ushort4 o = {f2b(v.x), f2b(v.y), f2b(v.z), f2b(v.w)};
            *(ushort4*)(pembb + i) = o;
        }
    } else if (blk < 2369) {
        int l = blk - 2113;
        tcvt_tile(Wq, qkvw, 512, 512, l & 15, l >> 4, tid, t);
    } else if (blk < 2881) {
        int l = blk - 2369;
        tcvt_tile(Wkv, qkvw + 512 * 512, 512, 1024, l & 31, l >> 5, tid, t);
    } else {
        int l = blk - 2881;
        tcvt_tile(Wout, Woutt, 512, 512, l & 15, l >> 4, tid, t);
    }
}

// ---------------------------------------------------------------------------
// MFMA GEMM: C[M,N] = A[M,K] @ Bt[N,K]^T  (bf16 in, fp32 acc)
// Templated on BN (tile = 64 x BN). BK=64 as 2x 32-wide sub-tiles (m97
// layout). 256 threads = 4 waves; per-wave output 32 x BN/2.
//   BN=128: QKV projection (grid-rich, 2-3 blocks/CU).
//   BN=64:  output projection — N=512 gave only 256 blocks = 1 block/CU at
//           BN=128; BN=64 doubles the grid to 512 = 2 blocks/CU (occupancy
//           was the gemm2 limiter, not per-block efficiency).
// Mode 1 (Cf!=null): fp32 out + bias. Mode 2 (qtb/ktb/vtb): QKV packing.
// ---------------------------------------------------------------------------
template<int BN>
__global__ __launch_bounds__(256)
void gemm_bt(const u16* __restrict__ A, const u16* __restrict__ Bt,
             int M, int N, int K,
             float* __restrict__ Cf, const float* __restrict__ bias,
             __bf16* __restrict__ qtb, __bf16* __restrict__ ktb,
             __bf16* __restrict__ vtb) {
    constexpr int NJ = BN / 32;          // B-frags per wave
    __shared__ __align__(16) u16 As[2][64][32];
    __shared__ __align__(16) u16 Bs[2][BN][32];
    const int tid = threadIdx.x, w = tid >> 6, lane = tid & 63;
    const int l15 = lane & 15, l4 = lane >> 4;
    const int wr = (w >> 1) * 32, wc = (w & 1) * (BN / 2);
    const int bm = blockIdx.y * 64, bn = blockIdx.x * BN;

    f4 acc[2][NJ];
    #pragma unroll
    for (int i = 0; i < 2; i++)
        #pragma unroll
        for (int j = 0; j < NJ; j++) acc[i][j] = (f4){0.f, 0.f, 0.f, 0.f};

    const int rS = lane >> 2;          // row within a 16-row staging group
    const int cS = (lane & 3) * 8;     // col (u16) within the 32-wide row

    for (int k0 = 0; k0 < K; k0 += 64) {
        #pragma unroll
        for (int ks = 0; ks < 2; ks++) {
            // A: sub-tile ks, rows [w*16, +16)
            gl_lds16(A + (size_t)(bm + w * 16 + rS) * K + k0 + ks * 32 + cS,
                     &As[ks][w * 16][0]);
            // B: sub-tile ks, BN/4 rows per wave in 16-row groups
            #pragma unroll
            for (int rb = 0; rb < BN / 4; rb += 16)
                gl_lds16(Bt + (size_t)(bn + w * (BN / 4) + rb + rS) * K
                             + k0 + ks * 32 + cS,
                         &Bs[ks][w * (BN / 4) + rb][0]);
        }
        __syncthreads();
        #pragma unroll
        for (int ks = 0; ks < 2; ks++) {
            bf8 af[2], bf[NJ];
            #pragma unroll
            for (int i = 0; i < 2; i++)
                af[i] = *(const bf8*)&As[ks][wr + i * 16 + l15][l4 * 8];
            #pragma unroll
            for (int j = 0; j < NJ; j++)
                bf[j] = *(const bf8*)&Bs[ks][wc + j * 16 + l15][l4 * 8];
            #pragma unroll
            for (int i = 0; i < 2; i++)
                #pragma unroll
                for (int j = 0; j < NJ; j++)
                    acc[i][j] = MFMA16(af[i], bf[j], acc[i][j]);
        }
        __syncthreads();
    }
    #pragma unroll
    for (int i = 0; i < 2; i++)
        #pragma unroll
        for (int j = 0; j < NJ; j++) {
            const int col = bn + wc + j * 16 + l15;
            const int row0 = bm + wr + i * 16 + l4 * 4;
            if (Cf) {
                #pragma unroll
                for (int reg = 0; reg < 4; reg++)
                    Cf[(size_t)(row0 + reg) * N + col] = acc[i][j][reg] + bias[col];
            } else if (col < 512) {
                int h = col >> 6, d = col & 63;
                #pragma unroll
                for (int reg = 0; reg < 4; reg++) {
                    int row = row0 + reg;
                    int b = row >> 10, t = row & 1023;
                    qtb[((((size_t)(b * 8 + h)) << 10 | t) << 6) | d] =
                        (__bf16)(acc[i][j][reg] * QSC);
                }
            } else if (col < 1024) {
                int h = (col >> 6) - 8, d = col & 63;
                #pragma unroll
                for (int reg = 0; reg < 4; reg++) {
                    int row = row0 + reg;
                    int b = row >> 10, t = row & 1023;
                    ktb[((((size_t)(b * 8 + h)) << 10 | t) << 6) | d] =
                        (__bf16)acc[i][j][reg];
                }
            } else {
                int h = (col >> 6) - 16, d = col & 63;
                int b = row0 >> 10, t = row0 & 1023;   // 4 rows share b (t aligned 4)
                __bf16 pk[4];
                #pragma unroll
                for (int reg = 0; reg < 4; reg++) pk[reg] = (__bf16)acc[i][j][reg];
                *(ushort4*)&vtb[(((size_t)(b * 8 + h) * 64 + d) << 10) | t] =
                    *(ushort4*)pk;
            }
        }
}

// ---------------------------------------------------------------------------
// Fused MFMA flash attention — 32x32 quadrant structure (R3) + latency-chain
// cuts (R4). Analysis: at 2 blocks/CU (grid-capped) the kernel is latency-
// bound on the barrier-locked serial chain; pipe sums (MFMA ~6us, LDS ~8us
// per CU) are far below the ~30us wall. Chain cuts, sync structure unchanged:
//  - Ring-gather loads HOISTED to iteration top: their addresses depend only
//    on t0 (not on QK^T's s16), and their slots were committed before the
//    previous barrier — so the 16 ds_read_u16 issue alongside the QK^T frag
//    reads and hide under the QK^T MFMAs (were serialized after them).
//  - Softmax halves INTERLEAVED with PV: p[0..7]->pa0->2 PV MFMAs, then
//    p[8..15]->pa1->2 PV MFMAs (TRANS/VALU overlaps MFMA pipe).
//  - s_setprio(1) around the QK^T..PV cluster (T5: cross-block arbitration;
//    2 independent blocks/CU are at different phases).
// Ring epoch safety (unchanged from R3): reads W(i) + refresh-writes W(i+1)
// span 191 < 256 slots -> hoisted reads stay race-free within the epoch.
// Grid: x = bh (XCD L2 locality), y = s0/64. LDS = 73,728 B -> 2 blocks/CU.
// ---------------------------------------------------------------------------
__global__ __launch_bounds__(256)
void attn_mfma(const u16* __restrict__ qtb, const u16* __restrict__ ktb,
               const u16* __restrict__ vtb, const u16* __restrict__ pembb,
               __bf16* __restrict__ ctxb) {
    __shared__ __align__(16) __bf16 Kb[2][64][72];  // K tiles [t][d]
    __shared__ __align__(16) __bf16 Vb[2][64][72];  // V tiles [d][t]
    __shared__ __align__(16) __bf16 Qd[256][72];    // qdot ring [j&255][s]

    const int tid = threadIdx.x, w = tid >> 6, lane = tid & 63;
    const int l31 = lane & 31, hi = lane >> 5;
    const int wq = w >> 1, wt = w & 1;
    const int bh = blockIdx.x, b = bh >> 3;
    const int s0 = blockIdx.y * 64;

    // Q frags (B-operand for swapped QK^T, A-operand for ring refresh)
    bf8 qb[4];
    {
        const u16* qp = qtb + ((size_t)bh * SEQ + s0 + wq * 32 + l31) * HD + hi * 8;
        #pragma unroll
        for (int st = 0; st < 4; st++) qb[st] = *(const bf8*)(qp + st * 16);
    }

    // ---- init ring: j in [s0+449, +127], wave covers (s=wq-half, j=wt-half)
    #pragma unroll
    for (int pass = 0; pass < 2; pass++) {
        const int jr = s0 + 449 + pass * 64 + wt * 32 + l31;
        const int jc = min(1024, max(0, jr));
        const u16* pp = pembb + (size_t)jc * HD + hi * 8;
        f16v acc;
        #pragma unroll
        for (int r = 0; r < 16; r++) acc[r] = 0.f;
        #pragma unroll
        for (int st = 0; st < 4; st++) {
            bf8 pj = *(const bf8*)(pp + st * 16);
            acc = MFMA32(qb[st], pj, acc);
        }
        #pragma unroll
        for (int o4 = 0; o4 < 4; o4++) {
            bf4 pk;
            #pragma unroll
            for (int r = 0; r < 4; r++) pk[r] = (__bf16)acc[o4 * 4 + r];
            *(bf4*)&Qd[jr & 255][wq * 32 + o4 * 8 + hi * 4] = pk;
        }
    }

    float l_lane = 0.f;
    f16v oo[2];
    #pragma unroll
    for (int dt = 0; dt < 2; dt++)
        #pragma unroll
        for (int r = 0; r < 16; r++) oo[dt][r] = 0.f;

    const u16* kbase = ktb + (size_t)bh * SEQ * HD;   // [t][d] packed
    const u16* vbase = vtb + (size_t)bh * HD * SEQ;   // [d][t]
    const int sr = tid >> 3, sc = (tid & 7) * 8;

    // ---- stage tile 0 into buf 0 ----
    *(bf8*)&Kb[0][sr][sc]      = *(const bf8*)(kbase + (size_t)sr * HD + sc);
    *(bf8*)&Kb[0][sr + 32][sc] = *(const bf8*)(kbase + (size_t)(sr + 32) * HD + sc);
    *(bf8*)&Vb[0][sr][sc]      = *(const bf8*)(vbase + (size_t)sr * SEQ + sc);
    *(bf8*)&Vb[0][sr + 32][sc] = *(const bf8*)(vbase + (size_t)(sr + 32) * SEQ + sc);
    __syncthreads();

    for (int i = 0; i < 16; i++) {
        const int cur = i & 1, nxt = cur ^ 1;
        const int t0 = i * 64, t1 = t0 + 64;
        const bool pre = (i < 15);
        bf8 kr0, kr1, vr0, vr1, pj0, pj1, pj2, pj3;
        const int jrn = s0 + 449 - 64 * (i + 1) + wt * 32 + l31;
        if (pre) {
            kr0 = *(const bf8*)(kbase + (size_t)(t1 + sr) * HD + sc);
            kr1 = *(const bf8*)(kbase + (size_t)(t1 + sr + 32) * HD + sc);
            vr0 = *(const bf8*)(vbase + (size_t)sr * SEQ + t1 + sc);
            vr1 = *(const bf8*)(vbase + (size_t)(sr + 32) * SEQ + t1 + sc);
            const int jc = min(1024, max(0, jrn));
            const u16* pp = pembb + (size_t)jc * HD + hi * 8;
            pj0 = *(const bf8*)(pp);
            pj1 = *(const bf8*)(pp + 16);
            pj2 = *(const bf8*)(pp + 32);
            pj3 = *(const bf8*)(pp + 48);
        }

        // ---- ALL LDS loads up front: K-frags, ring gather, V-frags ----
        bf8 ka[4];
        #pragma unroll
        for (int st = 0; st < 4; st++)
            ka[st] = *(const bf8*)&Kb[cur][wt * 32 + l31][st * 16 + hi * 8];
        const int jcst = (s0 - t0 + 512) + wq * 32 + l31 - wt * 32 - 4 * hi;
        const u16* qdc = (const u16*)&Qd[0][0] + wq * 32 + l31;
        u16 rg[16];
        #pragma unroll
        for (int r = 0; r < 16; r++) {
            const int pat = (r & 3) + 8 * (r >> 2);
            rg[r] = qdc[((jcst - pat) & 255) * 72];
        }
        bf8 vf00 = *(const bf8*)&Vb[cur][l31][wt * 32 + hi * 8];
        bf8 vf01 = *(const bf8*)&Vb[cur][l31][wt * 32 + 16 + hi * 8];
        bf8 vf10 = *(const bf8*)&Vb[cur][32 + l31][wt * 32 + hi * 8];
        bf8 vf11 = *(const bf8*)&Vb[cur][32 + l31][wt * 32 + 16 + hi * 8];

        __builtin_amdgcn_s_setprio(1);
        // ---- QK^T, swapped: lane holds q = wq*32+l31, 16 t's of wt-half ----
        f16v s16;
        #pragma unroll
        for (int r = 0; r < 16; r++) s16[r] = 0.f;
        #pragma unroll
        for (int st = 0; st < 4; st++) s16 = MFMA32(ka[st], qb[st], s16);

        // ---- softmax half 0 -> pa0 -> 2 PV MFMAs ----
        float p[16];
        float la = 0.f, lb = 0.f;
        #pragma unroll
        for (int r = 0; r < 8; r++) {
            float pv = fexp2(s16[r] + b2f(rg[r]));
            p[r] = pv; la += pv;
        }
        unsigned w00 = cvtpk_bf16(p[0], p[1]), w01 = cvtpk_bf16(p[2], p[3]);
        unsigned w10 = cvtpk_bf16(p[4], p[5]), w11 = cvtpk_bf16(p[6], p[7]);
        swap32(w00, w10); swap32(w01, w11);
        union { unsigned u[4]; bf8 v; } pa0, pa1;
        pa0.u[0] = w00; pa0.u[1] = w01; pa0.u[2] = w10; pa0.u[3] = w11;
        oo[0] = MFMA32(pa0.v, vf00, oo[0]);
        oo[1] = MFMA32(pa0.v, vf10, oo[1]);
        // ---- softmax half 1 -> pa1 -> 2 PV MFMAs ----
        #pragma unroll
        for (int r = 8; r < 16; r++) {
            float pv = fexp2(s16[r] + b2f(rg[r]));
            p[r] = pv; lb += pv;
        }
        unsigned w20 = cvtpk_bf16(p[8],  p[9]),  w21 = cvtpk_bf16(p[10], p[11]);
        unsigned w30 = cvtpk_bf16(p[12], p[13]), w31 = cvtpk_bf16(p[14], p[15]);
        swap32(w20, w30); swap32(w21, w31);
        pa1.u[0] = w20; pa1.u[1] = w21; pa1.u[2] = w30; pa1.u[3] = w31;
        oo[0] = MFMA32(pa1.v, vf01, oo[0]);
        oo[1] = MFMA32(pa1.v, vf11, oo[1]);
        __builtin_amdgcn_s_setprio(0);
        l_lane += la + lb;

        // ---- ring refresh for next window (pemb frags already in regs) ----
        if (pre) {
            f16v rf;
            #pragma unroll
            for (int r = 0; r < 16; r++) rf[r] = 0.f;
            rf = MFMA32(qb[0], pj0, rf);
            rf = MFMA32(qb[1], pj1, rf);
            rf = MFMA32(qb[2], pj2, rf);
            rf = MFMA32(qb[3], pj3, rf);
            #pragma unroll
            for (int o4 = 0; o4 < 4; o4++) {
                bf4 pk;
                #pragma unroll
                for (int r = 0; r < 4; r++) pk[r] = (__bf16)rf[o4 * 4 + r];
                *(bf4*)&Qd[jrn & 255][wq * 32 + o4 * 8 + hi * 4] = pk;
            }
            // ---- commit prefetched K/V tile to buf nxt ----
            *(bf8*)&Kb[nxt][sr][sc]      = kr0;
            *(bf8*)&Kb[nxt][sr + 32][sc] = kr1;
            *(bf8*)&Vb[nxt][sr][sc]      = vr0;
            *(bf8*)&Vb[nxt][sr + 32][sc] = vr1;
        }
        __syncthreads();   // single barrier: staging visible, buffers released
    }

    // ---- epilogue: cross-half l, cross-wave O reduce (ring LDS reused),
    //      normalize, store ----
    float lsum = l_lane + __shfl_xor(l_lane, 32);
    float* Os = (float*)&Qd[0][0];          // ring is dead; reuse as scratch
    float* Ls = Os + 4096;
    if (lane < 32) Ls[(wq * 2 + wt) * 32 + l31] = lsum;
    if (wt == 0) {
        #pragma unroll
        for (int dt = 0; dt < 2; dt++)
            #pragma unroll
            for (int r = 0; r < 16; r++) {
                const int q = (r & 3) + 8 * (r >> 2) + 4 * hi;
                Os[(wq * 32 + q) * 64 + dt * 32 + l31] = oo[dt][r];
            }
    }
    __syncthreads();
    if (wt == 1) {
        const int h = bh & 7;
        #pragma unroll
        for (int r = 0; r < 16; r++) {
            const int q = (r & 3) + 8 * (r >> 2) + 4 * hi;
            const float li = 1.f / (Ls[wq * 64 + q] + Ls[wq * 64 + 32 + q]);
            #pragma unroll
            for (int dt = 0; dt < 2; dt++) {
                float v = (oo[dt][r] + Os[(wq * 32 + q) * 64 + dt * 32 + l31]) * li;
                ctxb[(size_t)(b * SEQ + s0 + wq * 32 + q) * DM + h * HD + dt * 32 + l31]
                    = (__bf16)v;
            }
        }
    }
}

// ---------------------------------------------------------------------------
extern "C" void kernel_launch(void* const* d_in, const int* in_sizes, int n_in,
                              void* d_out, int out_size, void* d_ws, size_t ws_size,
                              hipStream_t stream) {
    const float* x    = (const float*)d_in[0];
    // d_in[1] attn_mask: unused by the reference computation
    const float* Wq   = (const float*)d_in[2];
    const float* Wkv  = (const float*)d_in[3];
    const float* Wout = (const float*)d_in[4];
    const float* bout = (const float*)d_in[5];
    const float* pemb = (const float*)d_in[6];
    float* out = (float*)d_out;

    const int M = BATCH * SEQ;   // 4096
    u16* p = (u16*)d_ws;
    u16* xb    = p; p += (size_t)M * DM;          // 4096x512
    u16* qkvw  = p; p += (size_t)NQKV * DM;       // 1536x512 (Wq^T ++ Wkv^T)
    u16* Woutt = p; p += (size_t)DM * DM;         // 512x512
    u16* pembb = p; p += (size_t)1025 * HD;       // 1025x64
    u16* qtb   = p; p += (size_t)M * DM;          // 32x1024x64 packed q (scaled)
    u16* ktb   = p; p += (size_t)M * DM;          // 32x1024x64 packed K
    u16* vtb   = p; p += (size_t)M * DM;          // 32x64x1024 transposed V
    u16* ctxb  = p; p += (size_t)M * DM;          // 4096x512

    prep<<<3137, 256, 0, stream>>>(x, Wq, Wkv, Wout, pemb, xb, qkvw, Woutt, pembb);

    // QKV projection with fused q-scale / K-pack / V-transpose epilogue
    gemm_bt<128><<<dim3(NQKV / 128, M / 64), 256, 0, stream>>>(
        xb, qkvw, M, NQKV, DM, nullptr, nullptr,
        (__bf16*)qtb, (__bf16*)ktb, (__bf16*)vtb);

    // fused attention -> ctx; grid x=bh for XCD L2 locality
    attn_mfma<<<dim3(BATCH * NH, SEQ / 64), 256, 0, stream>>>(
        qtb, ktb, vtb, pembb, (__bf16*)ctxb);

    // out = ctx @ Wout + bout  (BN=64: 512 blocks = 2/CU vs 1/CU at BN=128)
    gemm_bt<64><<<dim3(DM / 64, M / 64), 256, 0, stream>>>(
        ctxb, Woutt, M, DM, DM, out, bout, nullptr, nullptr, nullptr);
}